// Round 4
// baseline (49.427 us; speedup 1.0000x reference)
//
#include <hip/hip_runtime.h>
#include <hip/hip_bf16.h>
#include <math.h>

#define NB 4
#define MA 256
#define NFS 128
#define KSEL 8
#define HID 256
#define NOUT 32
#define RCUT 5.0f
#define PI_F 3.14159265358979323846f

// Kernel 1: 256 blocks x 4 rows. a1/a2 scalars, P = h@Wp1[:128], Q = h@Wp1[128:],
// z/r copy, and Wp2 transpose (32 elements per block).
__global__ __launch_bounds__(256) void prep_kernel(
    const int* __restrict__ z, const float* __restrict__ r,
    const float* __restrict__ h, const float* __restrict__ Wa,
    const float* __restrict__ Wp1, const float* __restrict__ Wp2,
    float* __restrict__ out,
    float* __restrict__ a1, float* __restrict__ a2,
    float* __restrict__ P, float* __restrict__ Q,
    float* __restrict__ Wp2T) {
  const int b = blockIdx.x;        // rows 4b..4b+3
  const int t = threadIdx.x;       // 0..255
  const int r0 = 4 * b;
  const int wave = t >> 6, lane = t & 63;
  __shared__ __align__(16) float hsh[4][NFS];

  // load 4 rows of h (contiguous 512 floats) as float2
  ((float2*)hsh)[t] = ((const float2*)(h + (size_t)r0 * NFS))[t];
  __syncthreads();

  // a1/a2: wave w handles row r0+w
  {
    const float h0 = hsh[wave][lane], h1 = hsh[wave][lane + 64];
    float p1 = h0 * Wa[lane]       + h1 * Wa[lane + 64];
    float p2 = h0 * Wa[NFS + lane] + h1 * Wa[NFS + lane + 64];
#pragma unroll
    for (int off = 32; off > 0; off >>= 1) {
      p1 += __shfl_down(p1, off);
      p2 += __shfl_down(p2, off);
    }
    if (lane == 0) { a1[r0 + wave] = p1; a2[r0 + wave] = p2; }
  }
  // z/r copy for these 4 rows
  if (t < 4)  out[r0 + t] = (float)z[r0 + t];
  if (t < 12) out[NB * MA + r0 * 3 + t] = r[r0 * 3 + t];
  // Wp2 transpose: block b writes elements b*32 .. b*32+31 of Wp2T[o][hh]
  if (t < 32) {
    const int e = b * 32 + t;
    Wp2T[e] = Wp2[(e & 255) * NOUT + (e >> 8)];
  }

  // P,Q for 4 rows; thread owns column t of Wp1.
  float aP0 = 0.f, aP1 = 0.f, aP2 = 0.f, aP3 = 0.f;
  float aQ0 = 0.f, aQ1 = 0.f, aQ2 = 0.f, aQ3 = 0.f;
#pragma unroll 2
  for (int f4 = 0; f4 < NFS / 4; ++f4) {
    const float wt0 = Wp1[(4 * f4 + 0) * HID + t];
    const float wt1 = Wp1[(4 * f4 + 1) * HID + t];
    const float wt2 = Wp1[(4 * f4 + 2) * HID + t];
    const float wt3 = Wp1[(4 * f4 + 3) * HID + t];
    const float wb0 = Wp1[(NFS + 4 * f4 + 0) * HID + t];
    const float wb1 = Wp1[(NFS + 4 * f4 + 1) * HID + t];
    const float wb2 = Wp1[(NFS + 4 * f4 + 2) * HID + t];
    const float wb3 = Wp1[(NFS + 4 * f4 + 3) * HID + t];
    const float4 h0 = *(const float4*)&hsh[0][4 * f4];
    const float4 h1 = *(const float4*)&hsh[1][4 * f4];
    const float4 h2 = *(const float4*)&hsh[2][4 * f4];
    const float4 h3 = *(const float4*)&hsh[3][4 * f4];
    aP0 = fmaf(h0.x, wt0, fmaf(h0.y, wt1, fmaf(h0.z, wt2, fmaf(h0.w, wt3, aP0))));
    aP1 = fmaf(h1.x, wt0, fmaf(h1.y, wt1, fmaf(h1.z, wt2, fmaf(h1.w, wt3, aP1))));
    aP2 = fmaf(h2.x, wt0, fmaf(h2.y, wt1, fmaf(h2.z, wt2, fmaf(h2.w, wt3, aP2))));
    aP3 = fmaf(h3.x, wt0, fmaf(h3.y, wt1, fmaf(h3.z, wt2, fmaf(h3.w, wt3, aP3))));
    aQ0 = fmaf(h0.x, wb0, fmaf(h0.y, wb1, fmaf(h0.z, wb2, fmaf(h0.w, wb3, aQ0))));
    aQ1 = fmaf(h1.x, wb0, fmaf(h1.y, wb1, fmaf(h1.z, wb2, fmaf(h1.w, wb3, aQ1))));
    aQ2 = fmaf(h2.x, wb0, fmaf(h2.y, wb1, fmaf(h2.z, wb2, fmaf(h2.w, wb3, aQ2))));
    aQ3 = fmaf(h3.x, wb0, fmaf(h3.y, wb1, fmaf(h3.z, wb2, fmaf(h3.w, wb3, aQ3))));
  }
  P[(size_t)(r0 + 0) * HID + t] = aP0;
  P[(size_t)(r0 + 1) * HID + t] = aP1;
  P[(size_t)(r0 + 2) * HID + t] = aP2;
  P[(size_t)(r0 + 3) * HID + t] = aP3;
  Q[(size_t)(r0 + 0) * HID + t] = aQ0;
  Q[(size_t)(r0 + 1) * HID + t] = aQ1;
  Q[(size_t)(r0 + 2) * HID + t] = aQ2;
  Q[(size_t)(r0 + 3) * HID + t] = aQ3;
}

// Kernel 2: one block per (n,i). g -> wave0 denom+top8 -> dvk/hidden -> layer2.
__global__ __launch_bounds__(256) void main_kernel(
    const int* __restrict__ z, const float* __restrict__ r,
    const float* __restrict__ a1g, const float* __restrict__ a2g,
    const float* __restrict__ ba,
    const float* __restrict__ Pg, const float* __restrict__ Qg,
    const float* __restrict__ bp1,
    const float* __restrict__ Wp2T, const float* __restrict__ bp2,
    float* __restrict__ out) {
  const int row = blockIdx.x;   // n*MA + i
  const int n = row >> 8;
  const int i = row & 255;
  const int tid = threadIdx.x;
  const int lane = tid & 63;
  const int wave = tid >> 6;

  __shared__ float gsh[MA];
  __shared__ __align__(16) float hid_sh[KSEL][HID];
  __shared__ float att_sh[KSEL];
  __shared__ int   idx_sh[KSEL];
  __shared__ float dvk_sh[KSEL][3];

  // ---- g for all j (this thread's j = tid) ----
  const float rix = r[row * 3 + 0], riy = r[row * 3 + 1], riz = r[row * 3 + 2];
  {
    const int jg = n * MA + tid;
    const float dx = r[jg * 3 + 0] - rix;
    const float dy = r[jg * 3 + 1] - riy;
    const float dz = r[jg * 3 + 2] - riz;
    const float d = sqrtf(dx * dx + dy * dy + dz * dz);
    const int mi = (z[row] > -1) ? 1 : 0;
    const int mj = (z[jg] > -1) ? 1 : 0;
    const int mask = max(mi * mj - ((tid == i) ? 1 : 0), 0);
    float g = 0.0f;
    if (mask) {
      const float cf = 0.5f * (__cosf(PI_F * fminf(d, RCUT) / RCUT) + 1.0f);
      g = __expf(a1g[row] + cf * a2g[jg] + ba[0]);
    }
    gsh[tid] = g;
  }
  __syncthreads();

  // ---- wave 0: denom + top-8 entirely via shfl ----
  if (wave == 0) {
    float v0 = gsh[lane];
    float v1 = gsh[lane + 64];
    float v2 = gsh[lane + 128];
    float v3 = gsh[lane + 192];
    float s = (v0 + v1) + (v2 + v3);
#pragma unroll
    for (int off = 32; off > 0; off >>= 1) s += __shfl_xor(s, off);
    const float rden = 1.0f / fmaxf(s, 1e-8f);
#pragma unroll
    for (int k = 0; k < KSEL; k++) {
      float bv = v0; int bi = lane;
      if (v1 > bv) { bv = v1; bi = lane + 64; }
      if (v2 > bv) { bv = v2; bi = lane + 128; }
      if (v3 > bv) { bv = v3; bi = lane + 192; }
#pragma unroll
      for (int off = 32; off > 0; off >>= 1) {
        const float ov = __shfl_xor(bv, off);
        const int oi = __shfl_xor(bi, off);
        if (ov > bv || (ov == bv && oi < bi)) { bv = ov; bi = oi; }
      }
      if (lane == 0) { idx_sh[k] = bi; att_sh[k] = bv * rden; }
      const int slot = bi >> 6, who = bi & 63;
      if (lane == who) {
        if (slot == 0) v0 = -1.0f;
        else if (slot == 1) v1 = -1.0f;
        else if (slot == 2) v2 = -1.0f;
        else v3 = -1.0f;
      }
    }
  }
  __syncthreads();

  // ---- dvk (8 threads) ----
  if (tid < KSEL) {
    const int jg = n * MA + idx_sh[tid];
    const float dx = r[jg * 3 + 0] - rix;
    const float dy = r[jg * 3 + 1] - riy;
    const float dz = r[jg * 3 + 2] - riz;
    const float nrm = fmaxf(sqrtf(dx * dx + dy * dy + dz * dz), 1e-4f);
    dvk_sh[tid][0] = dx / nrm;
    dvk_sh[tid][1] = dy / nrm;
    dvk_sh[tid][2] = dz / nrm;
  }

  // ---- hidden: hid[k][t] = silu(att_k*(P[i][t]+Q[jk][t]) + bp1[t]) ----
  {
    const float pi = Pg[(size_t)row * HID + tid];
    const float bb = bp1[tid];
#pragma unroll
    for (int k = 0; k < KSEL; k++) {
      const float q = Qg[(size_t)(n * MA + idx_sh[k]) * HID + tid];
      const float x = att_sh[k] * (pi + q) + bb;
      hid_sh[k][tid] = x / (1.0f + __expf(-x));
    }
  }
  __syncthreads();

  // ---- layer 2 (Wp2T rows, float4) + scale by dvk ----
  {
    const int k2 = tid >> 5;
    const int o = tid & 31;
    const float4* __restrict__ wrow = (const float4*)(Wp2T + (size_t)o * HID);
    const float4* __restrict__ hrow = (const float4*)hid_sh[k2];
    float acc = bp2[o];
#pragma unroll 8
    for (int q4 = 0; q4 < HID / 4; ++q4) {
      const float4 w = wrow[q4];
      const float4 hv = hrow[q4];
      acc = fmaf(hv.x, w.x, fmaf(hv.y, w.y, fmaf(hv.z, w.z, fmaf(hv.w, w.w, acc))));
    }
    float* cb = out + NB * MA + NB * MA * 3 + ((size_t)row * KSEL + k2) * (NOUT * 3) + o * 3;
    cb[0] = acc * dvk_sh[k2][0];
    cb[1] = acc * dvk_sh[k2][1];
    cb[2] = acc * dvk_sh[k2][2];
  }
}

extern "C" void kernel_launch(void* const* d_in, const int* in_sizes, int n_in,
                              void* d_out, int out_size, void* d_ws, size_t ws_size,
                              hipStream_t stream) {
  const int*   z   = (const int*)d_in[0];
  const float* r   = (const float*)d_in[1];
  const float* h   = (const float*)d_in[2];
  const float* Wa  = (const float*)d_in[3];
  const float* ba  = (const float*)d_in[4];
  const float* Wp1 = (const float*)d_in[5];
  const float* bp1 = (const float*)d_in[6];
  const float* Wp2 = (const float*)d_in[7];
  const float* bp2 = (const float*)d_in[8];
  float* out = (float*)d_out;

  float* a1   = (float*)d_ws;                  // 1024
  float* a2   = a1 + NB * MA;                  // 1024
  float* P    = a2 + NB * MA;                  // 1024*256
  float* Q    = P + (size_t)NB * MA * HID;     // 1024*256
  float* Wp2T = Q + (size_t)NB * MA * HID;     // 8192

  prep_kernel<<<NB * MA / 4, 256, 0, stream>>>(z, r, h, Wa, Wp1, Wp2, out, a1, a2, P, Q, Wp2T);
  main_kernel<<<NB * MA, 256, 0, stream>>>(z, r, a1, a2, ba, P, Q, bp1, Wp2T, bp2, out);
}

// Round 5
// 32.272 us; speedup vs baseline: 1.5315x; 1.5315x over previous
//
#include <hip/hip_runtime.h>
#include <hip/hip_bf16.h>
#include <math.h>

#define NB 4
#define MA 256
#define NFS 128
#define KSEL 8
#define HID 256
#define NOUT 32
#define RCUT 5.0f
#define PI_F 3.14159265358979323846f

// Kernel 1: 256 blocks x 4 rows. a1/a2 scalars, P = h@Wp1[:128], Q = h@Wp1[128:], z/r copy.
__global__ __launch_bounds__(256) void prep_kernel(
    const int* __restrict__ z, const float* __restrict__ r,
    const float* __restrict__ h, const float* __restrict__ Wa,
    const float* __restrict__ Wp1,
    float* __restrict__ out,
    float* __restrict__ a1, float* __restrict__ a2,
    float* __restrict__ P, float* __restrict__ Q) {
  const int b = blockIdx.x;        // rows 4b..4b+3
  const int t = threadIdx.x;       // 0..255
  const int r0 = 4 * b;
  const int wave = t >> 6, lane = t & 63;
  __shared__ __align__(16) float hsh[4][NFS];

  ((float2*)hsh)[t] = ((const float2*)(h + (size_t)r0 * NFS))[t];
  __syncthreads();

  {
    const float h0 = hsh[wave][lane], h1 = hsh[wave][lane + 64];
    float p1 = h0 * Wa[lane]       + h1 * Wa[lane + 64];
    float p2 = h0 * Wa[NFS + lane] + h1 * Wa[NFS + lane + 64];
#pragma unroll
    for (int off = 32; off > 0; off >>= 1) {
      p1 += __shfl_down(p1, off);
      p2 += __shfl_down(p2, off);
    }
    if (lane == 0) { a1[r0 + wave] = p1; a2[r0 + wave] = p2; }
  }
  if (t < 4)  out[r0 + t] = (float)z[r0 + t];
  if (t < 12) out[NB * MA + r0 * 3 + t] = r[r0 * 3 + t];

  float aP0 = 0.f, aP1 = 0.f, aP2 = 0.f, aP3 = 0.f;
  float aQ0 = 0.f, aQ1 = 0.f, aQ2 = 0.f, aQ3 = 0.f;
#pragma unroll 2
  for (int f4 = 0; f4 < NFS / 4; ++f4) {
    const float wt0 = Wp1[(4 * f4 + 0) * HID + t];
    const float wt1 = Wp1[(4 * f4 + 1) * HID + t];
    const float wt2 = Wp1[(4 * f4 + 2) * HID + t];
    const float wt3 = Wp1[(4 * f4 + 3) * HID + t];
    const float wb0 = Wp1[(NFS + 4 * f4 + 0) * HID + t];
    const float wb1 = Wp1[(NFS + 4 * f4 + 1) * HID + t];
    const float wb2 = Wp1[(NFS + 4 * f4 + 2) * HID + t];
    const float wb3 = Wp1[(NFS + 4 * f4 + 3) * HID + t];
    const float4 h0 = *(const float4*)&hsh[0][4 * f4];
    const float4 h1 = *(const float4*)&hsh[1][4 * f4];
    const float4 h2 = *(const float4*)&hsh[2][4 * f4];
    const float4 h3 = *(const float4*)&hsh[3][4 * f4];
    aP0 = fmaf(h0.x, wt0, fmaf(h0.y, wt1, fmaf(h0.z, wt2, fmaf(h0.w, wt3, aP0))));
    aP1 = fmaf(h1.x, wt0, fmaf(h1.y, wt1, fmaf(h1.z, wt2, fmaf(h1.w, wt3, aP1))));
    aP2 = fmaf(h2.x, wt0, fmaf(h2.y, wt1, fmaf(h2.z, wt2, fmaf(h2.w, wt3, aP2))));
    aP3 = fmaf(h3.x, wt0, fmaf(h3.y, wt1, fmaf(h3.z, wt2, fmaf(h3.w, wt3, aP3))));
    aQ0 = fmaf(h0.x, wb0, fmaf(h0.y, wb1, fmaf(h0.z, wb2, fmaf(h0.w, wb3, aQ0))));
    aQ1 = fmaf(h1.x, wb0, fmaf(h1.y, wb1, fmaf(h1.z, wb2, fmaf(h1.w, wb3, aQ1))));
    aQ2 = fmaf(h2.x, wb0, fmaf(h2.y, wb1, fmaf(h2.z, wb2, fmaf(h2.w, wb3, aQ2))));
    aQ3 = fmaf(h3.x, wb0, fmaf(h3.y, wb1, fmaf(h3.z, wb2, fmaf(h3.w, wb3, aQ3))));
  }
  P[(size_t)(r0 + 0) * HID + t] = aP0;
  P[(size_t)(r0 + 1) * HID + t] = aP1;
  P[(size_t)(r0 + 2) * HID + t] = aP2;
  P[(size_t)(r0 + 3) * HID + t] = aP3;
  Q[(size_t)(r0 + 0) * HID + t] = aQ0;
  Q[(size_t)(r0 + 1) * HID + t] = aQ1;
  Q[(size_t)(r0 + 2) * HID + t] = aQ2;
  Q[(size_t)(r0 + 3) * HID + t] = aQ3;
}

// Kernel 2: one block per (n,i). Wp2->LDS stage; g -> wave0 top8 -> hidden -> layer2(LDS).
__global__ __launch_bounds__(256) void main_kernel(
    const int* __restrict__ z, const float* __restrict__ r,
    const float* __restrict__ a1g, const float* __restrict__ a2g,
    const float* __restrict__ ba,
    const float* __restrict__ Pg, const float* __restrict__ Qg,
    const float* __restrict__ bp1,
    const float* __restrict__ Wp2g, const float* __restrict__ bp2,
    float* __restrict__ out) {
  const int row = blockIdx.x;   // n*MA + i
  const int n = row >> 8;
  const int i = row & 255;
  const int tid = threadIdx.x;
  const int lane = tid & 63;
  const int wave = tid >> 6;

  __shared__ float gsh[MA];
  __shared__ __align__(16) float hid_sh[KSEL][HID];
  __shared__ __align__(16) float wsh[HID][NOUT];   // Wp2 staged, original layout
  __shared__ float att_sh[KSEL];
  __shared__ int   idx_sh[KSEL];
  __shared__ float dvk_sh[KSEL][3];

  // ---- stage Wp2 (8192 floats) into LDS, coalesced float4 ----
  {
    const float4* __restrict__ src = (const float4*)Wp2g;
    float4* dst = (float4*)wsh;
#pragma unroll
    for (int j = 0; j < 8; ++j) dst[tid + 256 * j] = src[tid + 256 * j];
  }

  // ---- g for all j (this thread's j = tid) ----
  const float rix = r[row * 3 + 0], riy = r[row * 3 + 1], riz = r[row * 3 + 2];
  {
    const int jg = n * MA + tid;
    const float dx = r[jg * 3 + 0] - rix;
    const float dy = r[jg * 3 + 1] - riy;
    const float dz = r[jg * 3 + 2] - riz;
    const float d = sqrtf(dx * dx + dy * dy + dz * dz);
    const int mi = (z[row] > -1) ? 1 : 0;
    const int mj = (z[jg] > -1) ? 1 : 0;
    const int mask = max(mi * mj - ((tid == i) ? 1 : 0), 0);
    float g = 0.0f;
    if (mask) {
      const float cf = 0.5f * (__cosf(PI_F * fminf(d, RCUT) / RCUT) + 1.0f);
      g = __expf(a1g[row] + cf * a2g[jg] + ba[0]);
    }
    gsh[tid] = g;
  }
  __syncthreads();

  // ---- wave 0: denom + top-8 via shfl ----
  if (wave == 0) {
    float v0 = gsh[lane];
    float v1 = gsh[lane + 64];
    float v2 = gsh[lane + 128];
    float v3 = gsh[lane + 192];
    float s = (v0 + v1) + (v2 + v3);
#pragma unroll
    for (int off = 32; off > 0; off >>= 1) s += __shfl_xor(s, off);
    const float rden = 1.0f / fmaxf(s, 1e-8f);
#pragma unroll
    for (int k = 0; k < KSEL; k++) {
      float bv = v0; int bi = lane;
      if (v1 > bv) { bv = v1; bi = lane + 64; }
      if (v2 > bv) { bv = v2; bi = lane + 128; }
      if (v3 > bv) { bv = v3; bi = lane + 192; }
#pragma unroll
      for (int off = 32; off > 0; off >>= 1) {
        const float ov = __shfl_xor(bv, off);
        const int oi = __shfl_xor(bi, off);
        if (ov > bv || (ov == bv && oi < bi)) { bv = ov; bi = oi; }
      }
      if (lane == 0) { idx_sh[k] = bi; att_sh[k] = bv * rden; }
      const int slot = bi >> 6, who = bi & 63;
      if (lane == who) {
        if (slot == 0) v0 = -1.0f;
        else if (slot == 1) v1 = -1.0f;
        else if (slot == 2) v2 = -1.0f;
        else v3 = -1.0f;
      }
    }
  }
  __syncthreads();

  // ---- dvk (8 threads) ----
  if (tid < KSEL) {
    const int jg = n * MA + idx_sh[tid];
    const float dx = r[jg * 3 + 0] - rix;
    const float dy = r[jg * 3 + 1] - riy;
    const float dz = r[jg * 3 + 2] - riz;
    const float nrm = fmaxf(sqrtf(dx * dx + dy * dy + dz * dz), 1e-4f);
    dvk_sh[tid][0] = dx / nrm;
    dvk_sh[tid][1] = dy / nrm;
    dvk_sh[tid][2] = dz / nrm;
  }

  // ---- hidden: hid[k][t] = silu(att_k*(P[i][t]+Q[jk][t]) + bp1[t]) ----
  {
    const float pi = Pg[(size_t)row * HID + tid];
    const float bb = bp1[tid];
#pragma unroll
    for (int k = 0; k < KSEL; k++) {
      const float q = Qg[(size_t)(n * MA + idx_sh[k]) * HID + tid];
      const float x = att_sh[k] * (pi + q) + bb;
      hid_sh[k][tid] = x / (1.0f + __expf(-x));
    }
  }
  __syncthreads();

  // ---- layer 2 from LDS: thread = (o4 = 4 outputs, chunk = 64 hh, k) ----
  {
    const int o4 = tid & 7;
    const int chunk = (tid >> 3) & 3;
    const int k2 = tid >> 5;
    float4 acc = make_float4(0.f, 0.f, 0.f, 0.f);
    const float4* __restrict__ hrow = (const float4*)&hid_sh[k2][chunk * 64];
    const float4* __restrict__ wbase = (const float4*)wsh;   // row hh -> 8 float4
#pragma unroll
    for (int q4 = 0; q4 < 16; ++q4) {
      const int q4r = (q4 + 2 * chunk) & 15;          // spread hid banks across chunks
      const float4 hv = hrow[q4r];
      const int hh = chunk * 64 + q4r * 4;
      const float4 w0 = wbase[(hh + 0) * 8 + o4];
      const float4 w1 = wbase[(hh + 1) * 8 + o4];
      const float4 w2 = wbase[(hh + 2) * 8 + o4];
      const float4 w3 = wbase[(hh + 3) * 8 + o4];
      acc.x = fmaf(hv.x, w0.x, fmaf(hv.y, w1.x, fmaf(hv.z, w2.x, fmaf(hv.w, w3.x, acc.x))));
      acc.y = fmaf(hv.x, w0.y, fmaf(hv.y, w1.y, fmaf(hv.z, w2.y, fmaf(hv.w, w3.y, acc.y))));
      acc.z = fmaf(hv.x, w0.z, fmaf(hv.y, w1.z, fmaf(hv.z, w2.z, fmaf(hv.w, w3.z, acc.z))));
      acc.w = fmaf(hv.x, w0.w, fmaf(hv.y, w1.w, fmaf(hv.z, w2.w, fmaf(hv.w, w3.w, acc.w))));
    }
    // reduce across chunk (lane bits 3,4)
#pragma unroll
    for (int off = 8; off <= 16; off <<= 1) {
      acc.x += __shfl_xor(acc.x, off);
      acc.y += __shfl_xor(acc.y, off);
      acc.z += __shfl_xor(acc.z, off);
      acc.w += __shfl_xor(acc.w, off);
    }
    if (chunk == 0) {
      const float4 bq = ((const float4*)bp2)[o4];
      acc.x += bq.x; acc.y += bq.y; acc.z += bq.z; acc.w += bq.w;
      const float dx = dvk_sh[k2][0], dy = dvk_sh[k2][1], dz = dvk_sh[k2][2];
      float4* cb = (float4*)(out + NB * MA + NB * MA * 3 +
                             ((size_t)row * KSEL + k2) * (NOUT * 3) + o4 * 12);
      cb[0] = make_float4(acc.x * dx, acc.x * dy, acc.x * dz, acc.y * dx);
      cb[1] = make_float4(acc.y * dy, acc.y * dz, acc.z * dx, acc.z * dy);
      cb[2] = make_float4(acc.z * dz, acc.w * dx, acc.w * dy, acc.w * dz);
    }
  }
}

extern "C" void kernel_launch(void* const* d_in, const int* in_sizes, int n_in,
                              void* d_out, int out_size, void* d_ws, size_t ws_size,
                              hipStream_t stream) {
  const int*   z   = (const int*)d_in[0];
  const float* r   = (const float*)d_in[1];
  const float* h   = (const float*)d_in[2];
  const float* Wa  = (const float*)d_in[3];
  const float* ba  = (const float*)d_in[4];
  const float* Wp1 = (const float*)d_in[5];
  const float* bp1 = (const float*)d_in[6];
  const float* Wp2 = (const float*)d_in[7];
  const float* bp2 = (const float*)d_in[8];
  float* out = (float*)d_out;

  float* a1 = (float*)d_ws;                 // 1024
  float* a2 = a1 + NB * MA;                 // 1024
  float* P  = a2 + NB * MA;                 // 1024*256
  float* Q  = P + (size_t)NB * MA * HID;    // 1024*256

  prep_kernel<<<NB * MA / 4, 256, 0, stream>>>(z, r, h, Wa, Wp1, out, a1, a2, P, Q);
  main_kernel<<<NB * MA, 256, 0, stream>>>(z, r, a1, a2, ba, P, Q, bp1, Wp2, bp2, out);
}

// Round 6
// 22.885 us; speedup vs baseline: 2.1598x; 1.4102x over previous
//
#include <hip/hip_runtime.h>
#include <hip/hip_bf16.h>
#include <math.h>

#define NB 4
#define MA 256
#define NFS 128
#define KSEL 8
#define HID 256
#define NOUT 32
#define RCUT 5.0f
#define PI_F 3.14159265358979323846f

// Kernel 1: 256 blocks x 4 rows. a1/a2 scalars, P = h@Wp1[:128], Q = h@Wp1[128:], z/r copy.
// Thread = (c = t&63 -> cols 4c..4c+3, fq = t>>6 -> f in [32fq, 32fq+32)).
// float4-coalesced Wp1 loads; f-quarter partials reduced via LDS.
__global__ __launch_bounds__(256) void prep_kernel(
    const int* __restrict__ z, const float* __restrict__ r,
    const float* __restrict__ h, const float* __restrict__ Wa,
    const float* __restrict__ Wp1,
    float* __restrict__ out,
    float* __restrict__ a1, float* __restrict__ a2,
    float* __restrict__ P, float* __restrict__ Q) {
  const int b = blockIdx.x;        // rows 4b..4b+3
  const int t = threadIdx.x;       // 0..255
  const int r0 = 4 * b;
  const int wave = t >> 6, lane = t & 63;
  const int c = t & 63, fq = t >> 6;

  __shared__ __align__(16) float hsh[4][NFS];
  __shared__ __align__(16) float psumP[4][4][HID];   // [fq][row][col] 16 KB
  __shared__ __align__(16) float psumQ[4][4][HID];   // 16 KB

  // load 4 rows of h (contiguous 512 floats) as float2
  ((float2*)hsh)[t] = ((const float2*)(h + (size_t)r0 * NFS))[t];
  __syncthreads();

  // a1/a2: wave w handles row r0+w
  {
    const float h0 = hsh[wave][lane], h1 = hsh[wave][lane + 64];
    float p1 = h0 * Wa[lane]       + h1 * Wa[lane + 64];
    float p2 = h0 * Wa[NFS + lane] + h1 * Wa[NFS + lane + 64];
#pragma unroll
    for (int off = 32; off > 0; off >>= 1) {
      p1 += __shfl_down(p1, off);
      p2 += __shfl_down(p2, off);
    }
    if (lane == 0) { a1[r0 + wave] = p1; a2[r0 + wave] = p2; }
  }
  if (t < 4)  out[r0 + t] = (float)z[r0 + t];
  if (t < 12) out[NB * MA + r0 * 3 + t] = r[r0 * 3 + t];

  // P/Q partials over this thread's f-quarter
  float4 accP[4] = {make_float4(0,0,0,0), make_float4(0,0,0,0),
                    make_float4(0,0,0,0), make_float4(0,0,0,0)};
  float4 accQ[4] = {make_float4(0,0,0,0), make_float4(0,0,0,0),
                    make_float4(0,0,0,0), make_float4(0,0,0,0)};
#pragma unroll 4
  for (int ff = 0; ff < 32; ++ff) {
    const int f = fq * 32 + ff;
    const float4 wt = *(const float4*)&Wp1[(size_t)f * HID + 4 * c];
    const float4 wb = *(const float4*)&Wp1[(size_t)(f + NFS) * HID + 4 * c];
#pragma unroll
    for (int rr = 0; rr < 4; ++rr) {
      const float hv = hsh[rr][f];     // LDS broadcast (uniform across wave)
      accP[rr].x = fmaf(hv, wt.x, accP[rr].x);
      accP[rr].y = fmaf(hv, wt.y, accP[rr].y);
      accP[rr].z = fmaf(hv, wt.z, accP[rr].z);
      accP[rr].w = fmaf(hv, wt.w, accP[rr].w);
      accQ[rr].x = fmaf(hv, wb.x, accQ[rr].x);
      accQ[rr].y = fmaf(hv, wb.y, accQ[rr].y);
      accQ[rr].z = fmaf(hv, wb.z, accQ[rr].z);
      accQ[rr].w = fmaf(hv, wb.w, accQ[rr].w);
    }
  }
#pragma unroll
  for (int rr = 0; rr < 4; ++rr) {
    *(float4*)&psumP[fq][rr][4 * c] = accP[rr];
    *(float4*)&psumQ[fq][rr][4 * c] = accQ[rr];
  }
  __syncthreads();

  // final reduce over fq + store: thread -> (row = t>>6, cols 4c..4c+3)
  {
    const int r2 = t >> 6, c2 = t & 63;
    float4 sP = *(const float4*)&psumP[0][r2][4 * c2];
    float4 sQ = *(const float4*)&psumQ[0][r2][4 * c2];
#pragma unroll
    for (int q = 1; q < 4; ++q) {
      const float4 pP = *(const float4*)&psumP[q][r2][4 * c2];
      const float4 pQ = *(const float4*)&psumQ[q][r2][4 * c2];
      sP.x += pP.x; sP.y += pP.y; sP.z += pP.z; sP.w += pP.w;
      sQ.x += pQ.x; sQ.y += pQ.y; sQ.z += pQ.z; sQ.w += pQ.w;
    }
    *(float4*)&P[(size_t)(r0 + r2) * HID + 4 * c2] = sP;
    *(float4*)&Q[(size_t)(r0 + r2) * HID + 4 * c2] = sQ;
  }
}

// Kernel 2: one block per (n,i). g -> wave0 top8 -> dvk/hidden -> layer2 (broadcast scheme).
__global__ __launch_bounds__(256) void main_kernel(
    const int* __restrict__ z, const float* __restrict__ r,
    const float* __restrict__ a1g, const float* __restrict__ a2g,
    const float* __restrict__ ba,
    const float* __restrict__ Pg, const float* __restrict__ Qg,
    const float* __restrict__ bp1,
    const float* __restrict__ Wp2g, const float* __restrict__ bp2,
    float* __restrict__ out) {
  const int row = blockIdx.x;   // n*MA + i
  const int n = row >> 8;
  const int i = row & 255;
  const int tid = threadIdx.x;
  const int lane = tid & 63;
  const int wave = tid >> 6;

  __shared__ float gsh[MA];
  __shared__ __align__(16) float hid_sh[KSEL][HID];
  __shared__ float psum2[8][KSEL][NOUT];   // [chunk][k][o] 8 KB
  __shared__ float att_sh[KSEL];
  __shared__ int   idx_sh[KSEL];
  __shared__ float dvk_sh[KSEL][3];

  // layer-2 thread roles; issue the one-pass Wp2 loads EARLY (no dependencies)
  const int l2o = tid & 31;
  const int l2c = tid >> 5;      // 0..7, t-chunk [32c, 32c+32)
  float wreg[32];
#pragma unroll
  for (int j = 0; j < 32; ++j) wreg[j] = Wp2g[(size_t)(32 * l2c + j) * NOUT + l2o];

  // ---- g for all j (this thread's j = tid) ----
  const float rix = r[row * 3 + 0], riy = r[row * 3 + 1], riz = r[row * 3 + 2];
  {
    const int jg = n * MA + tid;
    const float dx = r[jg * 3 + 0] - rix;
    const float dy = r[jg * 3 + 1] - riy;
    const float dz = r[jg * 3 + 2] - riz;
    const float d = sqrtf(dx * dx + dy * dy + dz * dz);
    const int mi = (z[row] > -1) ? 1 : 0;
    const int mj = (z[jg] > -1) ? 1 : 0;
    const int mask = max(mi * mj - ((tid == i) ? 1 : 0), 0);
    float g = 0.0f;
    if (mask) {
      const float cf = 0.5f * (__cosf(PI_F * fminf(d, RCUT) / RCUT) + 1.0f);
      g = __expf(a1g[row] + cf * a2g[jg] + ba[0]);
    }
    gsh[tid] = g;
  }
  __syncthreads();

  // ---- wave 0: denom + top-8 via shfl ----
  if (wave == 0) {
    float v0 = gsh[lane];
    float v1 = gsh[lane + 64];
    float v2 = gsh[lane + 128];
    float v3 = gsh[lane + 192];
    float s = (v0 + v1) + (v2 + v3);
#pragma unroll
    for (int off = 32; off > 0; off >>= 1) s += __shfl_xor(s, off);
    const float rden = 1.0f / fmaxf(s, 1e-8f);
#pragma unroll
    for (int k = 0; k < KSEL; k++) {
      float bv = v0; int bi = lane;
      if (v1 > bv) { bv = v1; bi = lane + 64; }
      if (v2 > bv) { bv = v2; bi = lane + 128; }
      if (v3 > bv) { bv = v3; bi = lane + 192; }
#pragma unroll
      for (int off = 32; off > 0; off >>= 1) {
        const float ov = __shfl_xor(bv, off);
        const int oi = __shfl_xor(bi, off);
        if (ov > bv || (ov == bv && oi < bi)) { bv = ov; bi = oi; }
      }
      if (lane == 0) { idx_sh[k] = bi; att_sh[k] = bv * rden; }
      const int slot = bi >> 6, who = bi & 63;
      if (lane == who) {
        if (slot == 0) v0 = -1.0f;
        else if (slot == 1) v1 = -1.0f;
        else if (slot == 2) v2 = -1.0f;
        else v3 = -1.0f;
      }
    }
  }
  __syncthreads();

  // ---- dvk (8 threads) ----
  if (tid < KSEL) {
    const int jg = n * MA + idx_sh[tid];
    const float dx = r[jg * 3 + 0] - rix;
    const float dy = r[jg * 3 + 1] - riy;
    const float dz = r[jg * 3 + 2] - riz;
    const float nrm = fmaxf(sqrtf(dx * dx + dy * dy + dz * dz), 1e-4f);
    dvk_sh[tid][0] = dx / nrm;
    dvk_sh[tid][1] = dy / nrm;
    dvk_sh[tid][2] = dz / nrm;
  }

  // ---- hidden: hid[k][t] = silu(att_k*(P[i][t]+Q[jk][t]) + bp1[t]) ----
  {
    const float pi = Pg[(size_t)row * HID + tid];
    const float bb = bp1[tid];
#pragma unroll
    for (int k = 0; k < KSEL; k++) {
      const float q = Qg[(size_t)(n * MA + idx_sh[k]) * HID + tid];
      const float x = att_sh[k] * (pi + q) + bb;
      hid_sh[k][tid] = x / (1.0f + __expf(-x));
    }
  }
  __syncthreads();

  // ---- layer 2, broadcast scheme: thread (o=l2o, chunk=l2c) covers t in [32c,32c+32) ----
  {
    float acc[KSEL];
#pragma unroll
    for (int k = 0; k < KSEL; ++k) acc[k] = 0.0f;
#pragma unroll
    for (int k = 0; k < KSEL; ++k) {
      const float4* __restrict__ hrow = (const float4*)&hid_sh[k][32 * l2c];
#pragma unroll
      for (int j4 = 0; j4 < 8; ++j4) {
        const float4 hv = hrow[j4];    // uniform across 32-lane group -> broadcast
        acc[k] = fmaf(hv.x, wreg[4 * j4 + 0],
                 fmaf(hv.y, wreg[4 * j4 + 1],
                 fmaf(hv.z, wreg[4 * j4 + 2],
                 fmaf(hv.w, wreg[4 * j4 + 3], acc[k]))));
      }
    }
#pragma unroll
    for (int k = 0; k < KSEL; ++k) psum2[l2c][k][l2o] = acc[k];
  }
  __syncthreads();

  // ---- final: thread (k = tid>>5, o = tid&31): sum chunks, bias, dvk scale, store ----
  {
    const int k2 = tid >> 5;
    const int o = tid & 31;
    float s = bp2[o];
#pragma unroll
    for (int cc = 0; cc < 8; ++cc) s += psum2[cc][k2][o];
    const float dx = dvk_sh[k2][0], dy = dvk_sh[k2][1], dz = dvk_sh[k2][2];
    float* cb = out + NB * MA + NB * MA * 3 +
                ((size_t)row * KSEL + k2) * (NOUT * 3) + o * 3;
    cb[0] = s * dx;
    cb[1] = s * dy;
    cb[2] = s * dz;
  }
}

extern "C" void kernel_launch(void* const* d_in, const int* in_sizes, int n_in,
                              void* d_out, int out_size, void* d_ws, size_t ws_size,
                              hipStream_t stream) {
  const int*   z   = (const int*)d_in[0];
  const float* r   = (const float*)d_in[1];
  const float* h   = (const float*)d_in[2];
  const float* Wa  = (const float*)d_in[3];
  const float* ba  = (const float*)d_in[4];
  const float* Wp1 = (const float*)d_in[5];
  const float* bp1 = (const float*)d_in[6];
  const float* Wp2 = (const float*)d_in[7];
  const float* bp2 = (const float*)d_in[8];
  float* out = (float*)d_out;

  float* a1 = (float*)d_ws;                 // 1024
  float* a2 = a1 + NB * MA;                 // 1024
  float* P  = a2 + NB * MA;                 // 1024*256
  float* Q  = P + (size_t)NB * MA * HID;    // 1024*256

  prep_kernel<<<NB * MA / 4, 256, 0, stream>>>(z, r, h, Wa, Wp1, out, a1, a2, P, Q);
  main_kernel<<<NB * MA, 256, 0, stream>>>(z, r, a1, a2, ba, P, Q, bp1, Wp2, bp2, out);
}